// Round 5
// baseline (889.199 us; speedup 1.0000x reference)
//
#include <hip/hip_runtime.h>

#define Bb 64
#define Nn 128
#define Ee 2048
#define Hh 256
#define Ll 6
#define TN 8192
#define TE 131072
#define EDGE 50
#define EKPAD 64

typedef __attribute__((ext_vector_type(4))) float f32x4;
typedef __attribute__((ext_vector_type(8))) __bf16 bf16x8;
typedef __attribute__((ext_vector_type(8))) unsigned short ushort8;

__device__ inline float b2f(unsigned short u) {
    union { unsigned u; float f; } v; v.u = ((unsigned)u) << 16; return v.f;
}
__device__ inline unsigned short f2b(float f) {
    union { float f; unsigned u; } v; v.f = f;
    unsigned r = v.u + 0x7fffu + ((v.u >> 16) & 1u);
    return (unsigned short)(r >> 16);
}
__device__ inline float spf(float x) {
    return fmaxf(x, 0.f) + __logf(1.f + __expf(-fabsf(x)));
}
__device__ inline float sspf(float x) {
    return spf(x) - 0.69314718055994530942f;
}

// ============ fused edge pipeline ============
// Edges pre-permuted to CSR (dst-grouped) order. Per block: 128 edges.
//   t    = ssp(Acsr @ W1T^T + b1)        (A staged in LDS; W1 from global/L2)
//   gate = t @ W2T^T + b2                 (t in LDS; W2 from global/L2)
//   msg  = gate * nmsg[src]               (nmsg 4MB -> L2 gather)
//   msumf[dst] += segment-sum(msg)        (uniform-branch scan + f32 atomics)
// All MFMA swapped-operand (verified R4): acc[.][.][j] = C[row=r16][col=kg*4+j].
__global__ __launch_bounds__(256, 2)
void fused_edge(const unsigned short* __restrict__ A,      // TE x 64, CSR order
                const unsigned short* __restrict__ W1T,    // 256 x 64
                const float* __restrict__ b1,
                const unsigned short* __restrict__ W2T,    // 256 x 256
                const float* __restrict__ b2,
                const unsigned short* __restrict__ nmsgb,  // TN x 256 bf16
                const int* __restrict__ gsrcs,             // CSR src ids
                const int* __restrict__ dstn,              // CSR dst ids
                float* __restrict__ msumf)                 // TN x 256 f32 (zeroed)
{
    __shared__ __align__(16) unsigned char smem[128 * 512];   // 64KB: A -> t -> msg
    __shared__ int sm_src[128];
    __shared__ int sm_dst[128];

    const int tid  = threadIdx.x;
    const int lane = tid & 63;
    const int w    = tid >> 6;
    const int r16  = lane & 15;
    const int kg   = lane >> 4;
    const long brow = (long)blockIdx.x * 128;

    // ---- phase 1: stage A (128x64 bf16 = 16KB) + index slices ----
    {
        const int lrow  = lane >> 3;
        const int lslot = lane & 7;
#pragma unroll
        for (int i = 0; i < 4; ++i) {                  // 16 chunks / 4 waves
            const int cc   = w * 4 + i;
            const int srow = cc * 8 + lrow;
            const int kch  = lslot ^ (srow & 7);
            const unsigned short* gp = A + (brow + srow) * 64 + kch * 8;
            unsigned short* lp = (unsigned short*)smem + cc * 512;
            __builtin_amdgcn_global_load_lds(
                (const __attribute__((address_space(1))) void*)gp,
                (__attribute__((address_space(3))) void*)lp, 16, 0, 0);
        }
        if (tid < 128) {
            sm_src[tid] = gsrcs[brow + tid];
            sm_dst[tid] = dstn[brow + tid];
        }
    }
    __syncthreads();

    // ---- phase 2: GEMM1 -> acc1[m][n] = t[w*32+m*16+r16][n*16+kg*4+j] ----
    f32x4 acc1[2][16];
#pragma unroll
    for (int m = 0; m < 2; ++m)
#pragma unroll
        for (int n = 0; n < 16; ++n) acc1[m][n] = f32x4{0.f, 0.f, 0.f, 0.f};

#pragma unroll
    for (int kk = 0; kk < 2; ++kk) {
        bf16x8 af[2];
#pragma unroll
        for (int m = 0; m < 2; ++m) {
            const int row = w * 32 + m * 16 + r16;
            const int slot = (kk * 4 + kg) ^ (row & 7);
            af[m] = *(const bf16x8*)((unsigned short*)smem + row * 64 + slot * 8);
        }
#pragma unroll
        for (int n = 0; n < 16; ++n) {
            bf16x8 wf = *(const bf16x8*)(W1T + (n * 16 + r16) * 64 + kk * 32 + kg * 8);
            acc1[0][n] = __builtin_amdgcn_mfma_f32_16x16x32_bf16(wf, af[0], acc1[0][n], 0, 0, 0);
            acc1[1][n] = __builtin_amdgcn_mfma_f32_16x16x32_bf16(wf, af[1], acc1[1][n], 0, 0, 0);
        }
    }
    __syncthreads();   // A dead; smem becomes t

    // ---- phase 3: t -> LDS (bias + ssp, 8B packs, XOR swizzle) ----
#pragma unroll
    for (int m = 0; m < 2; ++m) {
        const int row = w * 32 + m * 16 + r16;
#pragma unroll
        for (int n = 0; n < 16; ++n) {
            const int c0 = n * 16 + kg * 4;
            const f32x4 bv = *(const f32x4*)(b1 + c0);
            uint2 p;
            p.x = (unsigned)f2b(sspf(acc1[m][n][0] + bv[0])) |
                  ((unsigned)f2b(sspf(acc1[m][n][1] + bv[1])) << 16);
            p.y = (unsigned)f2b(sspf(acc1[m][n][2] + bv[2])) |
                  ((unsigned)f2b(sspf(acc1[m][n][3] + bv[3])) << 16);
            const int off = (row * 512 + c0 * 2) ^ ((row & 7) << 4);
            *(uint2*)(smem + off) = p;
        }
    }
    __syncthreads();

    // ---- phase 4: GEMM2 -> acc2[m][n] = gate[wr*64+m*16+r16][wc*128+n*16+kg*4+j] ----
    const int wr = w >> 1, wc = w & 1;
    f32x4 acc2[4][8];
#pragma unroll
    for (int m = 0; m < 4; ++m)
#pragma unroll
        for (int n = 0; n < 8; ++n) acc2[m][n] = f32x4{0.f, 0.f, 0.f, 0.f};

#pragma unroll
    for (int kk = 0; kk < 8; ++kk) {
        bf16x8 af[4];
#pragma unroll
        for (int m = 0; m < 4; ++m) {
            const int row = wr * 64 + m * 16 + r16;
            const int off = (row * 512 + kk * 64 + kg * 16) ^ ((row & 7) << 4);
            af[m] = *(const bf16x8*)(smem + off);
        }
#pragma unroll
        for (int n = 0; n < 8; ++n) {
            const int col = wc * 128 + n * 16 + r16;
            bf16x8 wf = *(const bf16x8*)(W2T + col * 256 + kk * 32 + kg * 8);
#pragma unroll
            for (int m = 0; m < 4; ++m)
                acc2[m][n] = __builtin_amdgcn_mfma_f32_16x16x32_bf16(wf, af[m], acc2[m][n], 0, 0, 0);
        }
    }
    __syncthreads();   // t dead; smem becomes msg

    // ---- phase 5: msg = (gate + b2) * nmsg[src] -> LDS ----
#pragma unroll
    for (int m = 0; m < 4; ++m) {
        const int row = wr * 64 + m * 16 + r16;
        const int src = sm_src[row];
#pragma unroll
        for (int n = 0; n < 8; ++n) {
            const int c0 = wc * 128 + n * 16 + kg * 4;
            const f32x4 bv = *(const f32x4*)(b2 + c0);
            const unsigned short* np = nmsgb + ((long)src << 8) + c0;
            unsigned short n0 = np[0], n1 = np[1], n2 = np[2], n3 = np[3];
            float v0 = (acc2[m][n][0] + bv[0]) * b2f(n0);
            float v1 = (acc2[m][n][1] + bv[1]) * b2f(n1);
            float v2 = (acc2[m][n][2] + bv[2]) * b2f(n2);
            float v3 = (acc2[m][n][3] + bv[3]) * b2f(n3);
            uint2 p;
            p.x = (unsigned)f2b(v0) | ((unsigned)f2b(v1) << 16);
            p.y = (unsigned)f2b(v2) | ((unsigned)f2b(v3) << 16);
            const int off = (row * 512 + c0 * 2) ^ ((row & 7) << 4);
            *(uint2*)(smem + off) = p;
        }
    }
    __syncthreads();

    // ---- phase 6: segment-sum per column (uniform branches) + atomics ----
    {
        const int c = tid;
        float sum = 0.f;
        int cur = sm_dst[0];
        for (int r = 0; r < 128; ++r) {
            const int dn = sm_dst[r];
            if (dn != cur) {
                atomicAdd(&msumf[(long)cur * 256 + c], sum);
                sum = 0.f;
                cur = dn;
            }
            const unsigned short u =
                *(const unsigned short*)(smem + ((r * 512 + c * 2) ^ ((r & 7) << 4)));
            sum += b2f(u);
        }
        atomicAdd(&msumf[(long)cur * 256 + c], sum);
    }
}

// GEMM: C = act(A @ WT^T + bias), N fixed 256 (R4-verified, node side + readout)
template <int ACT, int OUTMODE, int TM>
__global__ __launch_bounds__(256)
void gemm_k(const unsigned short* __restrict__ A,
            const unsigned short* __restrict__ WT,
            const float* __restrict__ bias,
            unsigned short* __restrict__ Cb,
            float* __restrict__ Xf,
            unsigned short* __restrict__ Xb,
            int M, int K)
{
    constexpr int BK  = 64;
    constexpr int TNc = 128;
    constexpr int MR  = TM / 32;
    constexpr int NR  = 4;
    constexpr int STAGE_B = (TM + TNc) * BK * 2;
    constexpr int EPI_B   = (OUTMODE == 2) ? TM * TNc * 4 : TM * TNc * 2;
    constexpr int SMEM_B  = STAGE_B > EPI_B ? STAGE_B : EPI_B;

    __shared__ __align__(16) unsigned char smem[SMEM_B];
    unsigned short* As = (unsigned short*)smem;
    unsigned short* Bs = As + TM * BK;

    const int tid  = threadIdx.x;
    const int lane = tid & 63;
    const int w    = tid >> 6;
    const int wr   = w >> 1, wc = w & 1;
    const int r16  = lane & 15;
    const int kg   = lane >> 4;

    const long brow = (long)blockIdx.y * TM;
    const int  bcol = blockIdx.x * TNc;

    constexpr int ACH = TM / 8;
    constexpr int NCH = ACH + TNc / 8;
    constexpr int IPW = NCH / 4;
    const int lrow  = lane >> 3;
    const int lslot = lane & 7;

    f32x4 acc[MR][NR];
#pragma unroll
    for (int m = 0; m < MR; ++m)
#pragma unroll
        for (int n = 0; n < NR; ++n) acc[m][n] = f32x4{0.f, 0.f, 0.f, 0.f};

    for (int k0 = 0; k0 < K; k0 += BK) {
        __syncthreads();
#pragma unroll
        for (int i = 0; i < IPW; ++i) {
            const int c    = w * IPW + i;
            const bool isA = c < ACH;
            const int cc   = isA ? c : c - ACH;
            const int srow = cc * 8 + lrow;
            const int kch  = lslot ^ (srow & 7);
            const unsigned short* gp = isA
                ? A  + (brow + srow) * (long)K + k0 + kch * 8
                : WT + (bcol + srow) * (long)K + k0 + kch * 8;
            unsigned short* lp = (isA ? As : Bs) + cc * 512;
            __builtin_amdgcn_global_load_lds(
                (const __attribute__((address_space(1))) void*)gp,
                (__attribute__((address_space(3))) void*)lp, 16, 0, 0);
        }
        __syncthreads();

        bf16x8 a[MR][2], b[NR][2];
#pragma unroll
        for (int m = 0; m < MR; ++m) {
            const int row = wr * (MR * 16) + m * 16 + r16;
            const unsigned short* base = As + row * BK;
#pragma unroll
            for (int kk = 0; kk < 2; ++kk) {
                const int slot = (kk * 4 + kg) ^ (row & 7);
                a[m][kk] = *(const bf16x8*)(base + slot * 8);
            }
        }
#pragma unroll
        for (int n = 0; n < NR; ++n) {
            const int row = wc * 64 + n * 16 + r16;
            const unsigned short* base = Bs + row * BK;
#pragma unroll
            for (int kk = 0; kk < 2; ++kk) {
                const int slot = (kk * 4 + kg) ^ (row & 7);
                b[n][kk] = *(const bf16x8*)(base + slot * 8);
            }
        }
#pragma unroll
        for (int kk = 0; kk < 2; ++kk)
#pragma unroll
            for (int m = 0; m < MR; ++m)
#pragma unroll
                for (int n = 0; n < NR; ++n)
                    acc[m][n] = __builtin_amdgcn_mfma_f32_16x16x32_bf16(
                        b[n][kk], a[m][kk], acc[m][n], 0, 0, 0);
    }

    __syncthreads();

    if (OUTMODE != 2) {
#pragma unroll
        for (int m = 0; m < MR; ++m) {
            const int row = wr * (MR * 16) + m * 16 + r16;
#pragma unroll
            for (int n = 0; n < NR; ++n) {
                const int colL = wc * 64 + n * 16 + kg * 4;
                const f32x4 bv = *(const f32x4*)(bias + bcol + colL);
                float v0 = acc[m][n][0] + bv[0];
                float v1 = acc[m][n][1] + bv[1];
                float v2 = acc[m][n][2] + bv[2];
                float v3 = acc[m][n][3] + bv[3];
                if (ACT) { v0 = sspf(v0); v1 = sspf(v1); v2 = sspf(v2); v3 = sspf(v3); }
                uint2 p;
                p.x = (unsigned)f2b(v0) | ((unsigned)f2b(v1) << 16);
                p.y = (unsigned)f2b(v2) | ((unsigned)f2b(v3) << 16);
                const int off = (row * 256 + colL * 2) ^ ((row & 7) << 4);
                *(uint2*)(smem + off) = p;
            }
        }
        __syncthreads();
        constexpr int ITER = TM / 16;
#pragma unroll
        for (int q = 0; q < ITER; ++q) {
            const int flat = q * 4096 + tid * 16;
            const int row = flat >> 8, cbyte = flat & 255;
            uint4 d = *(const uint4*)(smem + ((row * 256 + cbyte) ^ ((row & 7) << 4)));
            *(uint4*)((unsigned char*)Cb + (brow + row) * 512 + bcol * 2 + cbyte) = d;
        }
    } else {
#pragma unroll
        for (int m = 0; m < MR; ++m) {
            const int row = wr * (MR * 16) + m * 16 + r16;
#pragma unroll
            for (int n = 0; n < NR; ++n) {
                const int colL = wc * 64 + n * 16 + kg * 4;
                const f32x4 bv = *(const f32x4*)(bias + bcol + colL);
                f32x4 v = acc[m][n] + bv;
                const int off = (row * 512 + colL * 4) ^ ((row & 7) << 4);
                *(f32x4*)(smem + off) = v;
            }
        }
        __syncthreads();
        constexpr int ITER = TM / 8;
#pragma unroll
        for (int q = 0; q < ITER; ++q) {
            const int flat = q * 4096 + tid * 16;
            const int row = flat >> 9, cbyte = flat & 511;
            f32x4 v = *(const f32x4*)(smem + ((row * 512 + cbyte) ^ ((row & 7) << 4)));
            const long base = (brow + row) * 256 + bcol + (cbyte >> 2);
            f32x4 xo = *(const f32x4*)(Xf + base);
            f32x4 nx = xo + v;
            *(f32x4*)(Xf + base) = nx;
            uint2 p;
            p.x = (unsigned)f2b(nx[0]) | ((unsigned)f2b(nx[1]) << 16);
            p.y = (unsigned)f2b(nx[2]) | ((unsigned)f2b(nx[3]) << 16);
            *(uint2*)(Xb + base) = p;
        }
    }
}

// ---------------- small kernels ----------------
__global__ void k_offsets(const int* __restrict__ num_nodes, int* __restrict__ off) {
    __shared__ int s[Bb];
    int t = threadIdx.x;
    s[t] = num_nodes[t];
    __syncthreads();
    for (int d = 1; d < Bb; d <<= 1) {
        int v = (t >= d) ? s[t - d] : 0;
        __syncthreads();
        s[t] += v;
        __syncthreads();
    }
    off[t + 1] = s[t];
    if (t == 0) off[0] = 0;
}

__global__ void k_edgeprep(const int* __restrict__ edges, const int* __restrict__ off,
                           int* __restrict__ gsrc, int* __restrict__ gdst, int* __restrict__ cnt) {
    int ge = blockIdx.x * 256 + threadIdx.x;
    if (ge >= TE) return;
    int b = ge >> 11;
    int o = off[b];
    gsrc[ge] = edges[ge * 2 + 0] + o;
    int d = edges[ge * 2 + 1] + o;
    gdst[ge] = d;
    atomicAdd(&cnt[d], 1);
}

__global__ void k_scan(const int* __restrict__ cnt, int* __restrict__ coff, int* __restrict__ pos) {
    __shared__ int part[1024];
    int t = threadIdx.x;
    int loc[8];
    int s = 0;
#pragma unroll
    for (int j = 0; j < 8; ++j) { loc[j] = cnt[t * 8 + j]; s += loc[j]; }
    part[t] = s;
    __syncthreads();
    for (int d = 1; d < 1024; d <<= 1) {
        int v = (t >= d) ? part[t - d] : 0;
        __syncthreads();
        part[t] += v;
        __syncthreads();
    }
    int base = part[t] - s;
#pragma unroll
    for (int j = 0; j < 8; ++j) {
        int idx = t * 8 + j;
        coff[idx] = base;
        pos[idx]  = base;
        base += loc[j];
    }
    if (t == 1023) coff[TN] = part[1023];
}

__global__ void k_fill(const int* __restrict__ gdst, const int* __restrict__ gsrc,
                       int* __restrict__ pos, int* __restrict__ eidl,
                       int* __restrict__ gsrcs, int* __restrict__ dstn) {
    int ge = blockIdx.x * 256 + threadIdx.x;
    if (ge >= TE) return;
    int d = gdst[ge];
    int p = atomicAdd(&pos[d], 1);
    eidl[p]  = ge;
    gsrcs[p] = gsrc[ge];
    dstn[p]  = d;
}

// RBF written directly in CSR order (A for fused_edge is contiguous)
__global__ void k_rbf(const float* __restrict__ ef, const int* __restrict__ eidl,
                      unsigned short* __restrict__ erbf) {
    int gid = blockIdx.x * 256 + threadIdx.x;   // TE * 64
    int i = gid >> 6, k = gid & 63;
    int ge = eidl[i];
    float v = 0.f;
    if (k < EDGE) {
        float d = ef[ge];
        float t = d - 0.1f * (float)k;
        v = __expf(-50.f * t * t);
    }
    erbf[gid] = f2b(v);
}

__global__ void k_embed(const int* __restrict__ nodes, const float* __restrict__ embed,
                        float* __restrict__ x, unsigned short* __restrict__ xb) {
    int gid = blockIdx.x * 256 + threadIdx.x;
    int i = gid >> 8, c = gid & 255;
    float v = embed[(nodes[i] << 8) + c];
    x[gid] = v;
    xb[gid] = f2b(v);
}

__global__ void k_cvt(const float* __restrict__ f, unsigned short* __restrict__ b) {
    int gid = blockIdx.x * 256 + threadIdx.x;   // TN*256/4 threads
    f32x4 v = *(const f32x4*)(f + gid * 4);
    uint2 p;
    p.x = (unsigned)f2b(v[0]) | ((unsigned)f2b(v[1]) << 16);
    p.y = (unsigned)f2b(v[2]) | ((unsigned)f2b(v[3]) << 16);
    *(uint2*)(b + gid * 4) = p;
}

__global__ void k_wprep(const float* __restrict__ me_w1, const float* __restrict__ me_w2,
                        const float* __restrict__ mn_w1, const float* __restrict__ mn_w2,
                        const float* __restrict__ st_w1, const float* __restrict__ st_w2,
                        const float* __restrict__ ro_w1,
                        unsigned short* __restrict__ me1T, unsigned short* __restrict__ me2T,
                        unsigned short* __restrict__ mn1T, unsigned short* __restrict__ mn2T,
                        unsigned short* __restrict__ st1T, unsigned short* __restrict__ st2T,
                        unsigned short* __restrict__ ro1T) {
    int gid = blockIdx.x * 256 + threadIdx.x;
    const int S1 = Ll * 256 * EKPAD;
    if (gid < S1) {
        int i = gid / (256 * EKPAD);
        int r = gid % (256 * EKPAD);
        int n = r / EKPAD, k = r % EKPAD;
        float v = (k < EDGE) ? me_w1[(i * EDGE + k) * 256 + n] : 0.f;
        me1T[gid] = f2b(v);
        return;
    }
    gid -= S1;
    const int S2 = Ll * 256 * 256;
    const float* srcs[5] = { me_w2, mn_w1, mn_w2, st_w1, st_w2 };
    unsigned short* dsts[5] = { me2T, mn1T, mn2T, st1T, st2T };
#pragma unroll
    for (int q = 0; q < 5; ++q) {
        if (gid < S2) {
            int i = gid >> 16;
            int r = gid & 65535;
            int n = r >> 8, k = r & 255;
            dsts[q][gid] = f2b(srcs[q][(i << 16) + k * 256 + n]);
            return;
        }
        gid -= S2;
    }
    int n = gid >> 8, k = gid & 255;
    ro1T[gid] = f2b(ro_w1[k * 256 + n]);
}

__global__ void k_readout(const unsigned short* __restrict__ t, const float* __restrict__ w2,
                          const float* __restrict__ b2, const int* __restrict__ num_nodes,
                          const float* __restrict__ evw, const float* __restrict__ evb,
                          float* __restrict__ out) {
    __shared__ float red[256];
    int b = blockIdx.x, tid = threadIdx.x;
    const unsigned short* tb = t + (long)b * Nn * 256;
    float part = 0.f;
    for (int i = tid; i < Nn * 256; i += 256)
        part += b2f(tb[i]) * w2[i & 255];
    red[tid] = part;
    __syncthreads();
    for (int d = 128; d > 0; d >>= 1) {
        if (tid < d) red[tid] += red[tid + d];
        __syncthreads();
    }
    if (tid == 0) {
        float g = red[0] + (float)Nn * b2[0];
        g = g * 2.0f + (-1.5f) * (float)num_nodes[b];
        out[b * 4 + 0] = g * evw[0] + evb[0];
        out[b * 4 + 1] = spf(g * evw[1] + evb[1]);
        out[b * 4 + 2] = spf(g * evw[2] + evb[2]) + 1.f;
        out[b * 4 + 3] = spf(g * evw[3] + evb[3]);
    }
}

// ---------------- workspace layout ----------------
constexpr size_t al(size_t x) { return (x + 255) & ~(size_t)255; }
constexpr size_t O_OFF    = 0;
constexpr size_t O_GSRC   = al(O_OFF + 65 * 4);
constexpr size_t O_GDST   = al(O_GSRC + (size_t)TE * 4);
constexpr size_t O_CNT    = al(O_GDST + (size_t)TE * 4);
constexpr size_t O_COFF   = al(O_CNT + (size_t)TN * 4);
constexpr size_t O_POS    = al(O_COFF + (size_t)(TN + 1) * 4);
constexpr size_t O_EIDL   = al(O_POS + (size_t)TN * 4);
constexpr size_t O_GSRCS  = al(O_EIDL + (size_t)TE * 4);
constexpr size_t O_DSTN   = al(O_GSRCS + (size_t)TE * 4);
constexpr size_t O_ERBF   = al(O_DSTN + (size_t)TE * 4);
constexpr size_t O_ME1T   = al(O_ERBF + (size_t)TE * EKPAD * 2);
constexpr size_t O_ME2T   = al(O_ME1T + (size_t)Ll * 256 * EKPAD * 2);
constexpr size_t O_MN1T   = al(O_ME2T + (size_t)Ll * 256 * 256 * 2);
constexpr size_t O_MN2T   = al(O_MN1T + (size_t)Ll * 256 * 256 * 2);
constexpr size_t O_ST1T   = al(O_MN2T + (size_t)Ll * 256 * 256 * 2);
constexpr size_t O_ST2T   = al(O_ST1T + (size_t)Ll * 256 * 256 * 2);
constexpr size_t O_RO1T   = al(O_ST2T + (size_t)Ll * 256 * 256 * 2);
constexpr size_t O_X      = al(O_RO1T + (size_t)256 * 256 * 2);
constexpr size_t O_XB     = al(O_X + (size_t)TN * 256 * 4);
constexpr size_t O_TMPB   = al(O_XB + (size_t)TN * 256 * 2);
constexpr size_t O_NMSG   = al(O_TMPB + (size_t)TN * 256 * 2);
constexpr size_t O_MSUM   = al(O_NMSG + (size_t)TN * 256 * 2);
constexpr size_t O_MSUMF  = al(O_MSUM + (size_t)TN * 256 * 2);
constexpr size_t WS_NEED  = al(O_MSUMF + (size_t)TN * 256 * 4);

extern "C" void kernel_launch(void* const* d_in, const int* in_sizes, int n_in,
                              void* d_out, int out_size, void* d_ws, size_t ws_size,
                              hipStream_t stream) {
    if (ws_size < WS_NEED) return;

    const int*   nodes     = (const int*)d_in[0];
    const int*   num_nodes = (const int*)d_in[1];
    const int*   edges     = (const int*)d_in[2];
    const float* efeat     = (const float*)d_in[3];
    const float* embed     = (const float*)d_in[5];
    const float* me_w1 = (const float*)d_in[6],  *me_b1 = (const float*)d_in[7];
    const float* me_w2 = (const float*)d_in[8],  *me_b2 = (const float*)d_in[9];
    const float* mn_w1 = (const float*)d_in[10], *mn_b1 = (const float*)d_in[11];
    const float* mn_w2 = (const float*)d_in[12], *mn_b2 = (const float*)d_in[13];
    const float* st_w1 = (const float*)d_in[14], *st_b1 = (const float*)d_in[15];
    const float* st_w2 = (const float*)d_in[16], *st_b2 = (const float*)d_in[17];
    const float* ro_w1 = (const float*)d_in[18], *ro_b1 = (const float*)d_in[19];
    const float* ro_w2 = (const float*)d_in[20], *ro_b2 = (const float*)d_in[21];
    const float* ev_w  = (const float*)d_in[22], *ev_b  = (const float*)d_in[23];

    char* ws = (char*)d_ws;
    int* off   = (int*)(ws + O_OFF);
    int* gsrc  = (int*)(ws + O_GSRC);
    int* gdst  = (int*)(ws + O_GDST);
    int* cnt   = (int*)(ws + O_CNT);
    int* coff  = (int*)(ws + O_COFF);
    int* pos   = (int*)(ws + O_POS);
    int* eidl  = (int*)(ws + O_EIDL);
    int* gsrcs = (int*)(ws + O_GSRCS);
    int* dstn  = (int*)(ws + O_DSTN);
    unsigned short* erbf  = (unsigned short*)(ws + O_ERBF);
    unsigned short* me1T  = (unsigned short*)(ws + O_ME1T);
    unsigned short* me2T  = (unsigned short*)(ws + O_ME2T);
    unsigned short* mn1T  = (unsigned short*)(ws + O_MN1T);
    unsigned short* mn2T  = (unsigned short*)(ws + O_MN2T);
    unsigned short* st1T  = (unsigned short*)(ws + O_ST1T);
    unsigned short* st2T  = (unsigned short*)(ws + O_ST2T);
    unsigned short* ro1T  = (unsigned short*)(ws + O_RO1T);
    float*          x     = (float*)(ws + O_X);
    unsigned short* xb    = (unsigned short*)(ws + O_XB);
    unsigned short* tmpb  = (unsigned short*)(ws + O_TMPB);
    unsigned short* nmsgb = (unsigned short*)(ws + O_NMSG);
    unsigned short* msum  = (unsigned short*)(ws + O_MSUM);
    float*          msumf = (float*)(ws + O_MSUMF);
    float* out = (float*)d_out;

    hipMemsetAsync(cnt, 0, TN * 4, stream);
    k_offsets<<<1, Bb, 0, stream>>>(num_nodes, off);
    k_edgeprep<<<TE / 256, 256, 0, stream>>>(edges, off, gsrc, gdst, cnt);
    k_scan<<<1, 1024, 0, stream>>>(cnt, coff, pos);
    k_fill<<<TE / 256, 256, 0, stream>>>(gdst, gsrc, pos, eidl, gsrcs, dstn);
    k_rbf<<<(TE * EKPAD) / 256, 256, 0, stream>>>(efeat, eidl, erbf);
    k_embed<<<TN, 256, 0, stream>>>(nodes, embed, x, xb);
    {
        const int total = Ll * 256 * EKPAD + 5 * Ll * 256 * 256 + 256 * 256;
        k_wprep<<<total / 256, 256, 0, stream>>>(me_w1, me_w2, mn_w1, mn_w2, st_w1, st_w2, ro_w1,
                                                 me1T, me2T, mn1T, mn2T, st1T, st2T, ro1T);
    }

    const dim3 gN(2, TN / 64), blk(256);
    for (int i = 0; i < Ll; ++i) {
        gemm_k<1, 0, 64><<<gN, blk, 0, stream>>>(xb, mn1T + i * 65536, mn_b1 + i * 256,
                                                 tmpb, nullptr, nullptr, TN, 256);
        gemm_k<0, 0, 64><<<gN, blk, 0, stream>>>(tmpb, mn2T + i * 65536, mn_b2 + i * 256,
                                                 nmsgb, nullptr, nullptr, TN, 256);
        hipMemsetAsync(msumf, 0, (size_t)TN * 256 * 4, stream);
        fused_edge<<<TE / 128, 256, 0, stream>>>(erbf, me1T + i * 256 * EKPAD, me_b1 + i * 256,
                                                 me2T + i * 65536, me_b2 + i * 256,
                                                 nmsgb, gsrcs, dstn, msumf);
        k_cvt<<<(TN * 256 / 4) / 256, 256, 0, stream>>>(msumf, msum);
        gemm_k<1, 0, 64><<<gN, blk, 0, stream>>>(msum, st1T + i * 65536, st_b1 + i * 256,
                                                 tmpb, nullptr, nullptr, TN, 256);
        gemm_k<0, 2, 64><<<gN, blk, 0, stream>>>(tmpb, st2T + i * 65536, st_b2 + i * 256,
                                                 nullptr, x, xb, TN, 256);
    }

    gemm_k<1, 0, 64><<<gN, blk, 0, stream>>>(xb, ro1T, ro_b1, tmpb, nullptr, nullptr, TN, 256);
    k_readout<<<Bb, 256, 0, stream>>>(tmpb, ro_w2, ro_b2, num_nodes, ev_w, ev_b, out);
}